// Round 1
// baseline (388.130 us; speedup 1.0000x reference)
//
#include <hip/hip_runtime.h>

// UWNeRF RGB renderer: R rays x S=128 samples, fp32.
// One wave (64 lanes) per ray; lane L owns samples 2L, 2L+1.
// 7 fused exclusive prefix-sums via wave shfl scan, 10 fused reductions
// via butterfly. Memory-bound: ~470 MB read -> ~75 us floor at 6.3 TB/s.

constexpr int S = 128;

__global__ __launch_bounds__(256) void uwnerf_render(
    const float* __restrict__ densities,   // [R,S,1]
    const float* __restrict__ rgbs,        // [R,S,3]
    const float* __restrict__ veil,        // [R,S,3]
    const float* __restrict__ dcoef,       // [R,S,3]
    const float* __restrict__ bcoef,       // [R,S,3]
    const float* __restrict__ deltas,      // [R,S,1]
    float* __restrict__ out,               // [4,R,3]: rgb, restored, direct, backscatter
    int R)
{
    const int lane = threadIdx.x & 63;
    const int r = (blockIdx.x << 2) + (threadIdx.x >> 6);
    if (r >= R) return;

    const size_t b1 = (size_t)r * S + 2 * (size_t)lane;       // scalar arrays
    const size_t b3 = (size_t)r * S * 3 + 6 * (size_t)lane;   // 3-channel arrays

    const float2 den = *(const float2*)(densities + b1);
    const float2 dlt = *(const float2*)(deltas + b1);

    float rgb_[6], vl_[6], dcv[6], bcv[6];
#pragma unroll
    for (int i = 0; i < 3; ++i) {
        reinterpret_cast<float2*>(rgb_)[i] = *(const float2*)(rgbs  + b3 + 2 * i);
        reinterpret_cast<float2*>(vl_)[i]  = *(const float2*)(veil  + b3 + 2 * i);
        reinterpret_cast<float2*>(dcv)[i]  = *(const float2*)(dcoef + b3 + 2 * i);
        reinterpret_cast<float2*>(bcv)[i]  = *(const float2*)(bcoef + b3 + 2 * i);
    }

    // per-sample scan inputs: odd = delta*density; dd = delta*direct; bb = delta*backscatter
    const float odd0 = dlt.x * den.x;
    const float odd1 = dlt.y * den.y;

    // v0[j] = value at first sample of this lane; sc[j] = pair sum (scan operand)
    float v0[7], sc[7];
    v0[0] = odd0;  sc[0] = odd0 + odd1;
#pragma unroll
    for (int c = 0; c < 3; ++c) {
        const float a0 = dlt.x * dcv[c], a1 = dlt.y * dcv[3 + c];
        const float b0 = dlt.x * bcv[c], b1 = dlt.y * bcv[3 + c];
        v0[1 + c] = a0;  sc[1 + c] = a0 + a1;
        v0[4 + c] = b0;  sc[4 + c] = b0 + b1;
    }

    float orig[7];
#pragma unroll
    for (int j = 0; j < 7; ++j) orig[j] = sc[j];

    // fused Hillis-Steele inclusive scan of pair sums across 64 lanes
#pragma unroll
    for (int off = 1; off < 64; off <<= 1) {
        float t[7];
#pragma unroll
        for (int j = 0; j < 7; ++j) t[j] = __shfl_up(sc[j], off, 64);
        const bool p = (lane >= off);
#pragma unroll
        for (int j = 0; j < 7; ++j) sc[j] += p ? t[j] : 0.0f;
    }

    // exclusive prefix at sample 2L: inclusive - own pair
    float ex[7];
#pragma unroll
    for (int j = 0; j < 7; ++j) ex[j] = sc[j] - orig[j];
    // exclusive prefix at sample 2L+1 = ex[j] + v0[j]

    // object transmittance / alphas / weights
    const float T0 = __expf(-ex[0]);
    const float e0 = __expf(-odd0);
    const float e1 = __expf(-odd1);
    const float T1 = T0 * e0;
    const float w0 = (1.0f - e0) * T0;
    const float w1 = (1.0f - e1) * T1;

    // partial reductions: [0..2] restored, [3..5] direct_ray, [6..8] backscatter_obj, [9] wsum
    float red[10];
    red[9] = w0 + w1;
#pragma unroll
    for (int c = 0; c < 3; ++c) {
        const float da0 = __expf(-ex[1 + c]);             // direct atten at s0
        const float da1 = da0 * __expf(-v0[1 + c]);       // at s1
        const float bt0 = __expf(-ex[4 + c]);             // backscatter transmittance at s0
        const float bt1 = bt0 * __expf(-v0[4 + c]);       // at s1
        red[c]     = w0 * rgb_[c] + w1 * rgb_[3 + c];
        red[3 + c] = w0 * da0 * rgb_[c] + w1 * da1 * rgb_[3 + c];
        red[6 + c] = w0 * (1.0f - bt0) * vl_[c] + w1 * (1.0f - bt1) * vl_[3 + c];
    }

    // fused butterfly reduction -> every lane has totals
#pragma unroll
    for (int off = 32; off >= 1; off >>= 1) {
#pragma unroll
        for (int j = 0; j < 10; ++j) red[j] += __shfl_xor(red[j], off, 64);
    }

    // veiling_light at sample 0 lives in lane 0's vl_[0..2]; broadcast while all lanes active
    float vl0[3];
#pragma unroll
    for (int c = 0; c < 3; ++c) vl0[c] = __shfl(vl_[c], 0, 64);

    if (lane < 3) {
        const int c = lane;
        const float mask = fminf(fmaxf(red[9], 0.0f), 1.0f);
        const float bsr  = red[6 + c] + (1.0f - mask) * vl0[c];
        const size_t rc = (size_t)r * 3 + c;
        const size_t stride = (size_t)R * 3;
        out[rc]              = fminf(fmaxf(red[3 + c] + bsr, 0.0f), 1.0f); // rgb
        out[stride + rc]     = fminf(fmaxf(red[c],          0.0f), 1.0f); // restored
        out[2 * stride + rc] = fminf(fmaxf(red[3 + c],      0.0f), 1.0f); // direct
        out[3 * stride + rc] = fminf(fmaxf(bsr,             0.0f), 1.0f); // backscatter
    }
}

extern "C" void kernel_launch(void* const* d_in, const int* in_sizes, int n_in,
                              void* d_out, int out_size, void* d_ws, size_t ws_size,
                              hipStream_t stream) {
    const float* densities = (const float*)d_in[0];
    const float* rgbs      = (const float*)d_in[1];
    const float* veil      = (const float*)d_in[2];
    const float* dcoef     = (const float*)d_in[3];
    const float* bcoef     = (const float*)d_in[4];
    const float* deltas    = (const float*)d_in[5];
    float* out = (float*)d_out;

    const int R = in_sizes[0] / S;   // 65536
    dim3 grid((R + 3) / 4), block(256);
    uwnerf_render<<<grid, block, 0, stream>>>(densities, rgbs, veil, dcoef, bcoef,
                                              deltas, out, R);
}

// Round 2
// 384.612 us; speedup vs baseline: 1.0091x; 1.0091x over previous
//
#include <hip/hip_runtime.h>

// UWNeRF RGB renderer: R rays x S=128 samples, fp32.
// 32 lanes per ray (2 rays per wave), lane owns 4 contiguous samples.
// Local serial prefix in registers + 5-round width-32 shuffle scan of lane
// aggregates cuts cross-lane DS ops from ~105/ray to ~44/ray (R1 was
// DS-pipe / latency bound: VALUBusy 26%, HBM 20%, nothing saturated).

constexpr int S = 128;

__global__ __launch_bounds__(256) void uwnerf_render(
    const float* __restrict__ densities,   // [R,S,1]
    const float* __restrict__ rgbs,        // [R,S,3]
    const float* __restrict__ veil,        // [R,S,3]
    const float* __restrict__ dcoef,       // [R,S,3]
    const float* __restrict__ bcoef,       // [R,S,3]
    const float* __restrict__ deltas,      // [R,S,1]
    float* __restrict__ out,               // [4,R,3]: rgb, restored, direct, backscatter
    int R)
{
    const int lane = threadIdx.x & 63;
    const int l = lane & 31;          // lane within ray
    const int sub = lane >> 5;        // ray slot within wave
    const int r = blockIdx.x * 8 + (int)(threadIdx.x >> 6) * 2 + sub;
    if (r >= R) return;

    const size_t b1 = (size_t)r * S + 4 * (size_t)l;   // scalar arrays, 16B/lane
    const size_t b3 = b1 * 3;                          // channel arrays, 48B/lane (16B-aligned)

    const float4 den4 = *(const float4*)(densities + b1);
    const float4 dlt4 = *(const float4*)(deltas + b1);

    float rgbv[12], vlv[12], dcv[12], bcv[12];
#pragma unroll
    for (int i = 0; i < 3; ++i) {
        *(float4*)(rgbv + 4 * i) = *(const float4*)(rgbs  + b3 + 4 * i);
        *(float4*)(vlv  + 4 * i) = *(const float4*)(veil  + b3 + 4 * i);
        *(float4*)(dcv  + 4 * i) = *(const float4*)(dcoef + b3 + 4 * i);
        *(float4*)(bcv  + 4 * i) = *(const float4*)(bcoef + b3 + 4 * i);
    }

    const float dl[4] = {dlt4.x, dlt4.y, dlt4.z, dlt4.w};
    const float dn[4] = {den4.x, den4.y, den4.z, den4.w};

    // local exclusive prefixes (per-lane, in registers)
    float odd[4], cumO[4];
    float accO = 0.0f;
#pragma unroll
    for (int s = 0; s < 4; ++s) {
        odd[s] = dl[s] * dn[s];
        cumO[s] = accO;
        accO += odd[s];
    }

    float cumD[12], cumB[12], loc[7];
    loc[0] = accO;
#pragma unroll
    for (int c = 0; c < 3; ++c) {
        float ad = 0.0f, ab = 0.0f;
#pragma unroll
        for (int s = 0; s < 4; ++s) {
            const float dv = dl[s] * dcv[3 * s + c];
            const float bv = dl[s] * bcv[3 * s + c];
            cumD[4 * c + s] = ad; ad += dv;
            cumB[4 * c + s] = ab; ab += bv;
        }
        loc[1 + c] = ad;
        loc[4 + c] = ab;
    }

    // inclusive scan of 7 lane-aggregates within each 32-lane half
    float agg[7];
#pragma unroll
    for (int j = 0; j < 7; ++j) agg[j] = loc[j];
#pragma unroll
    for (int off = 1; off < 32; off <<= 1) {
        float t[7];
#pragma unroll
        for (int j = 0; j < 7; ++j) t[j] = __shfl_up(agg[j], off, 32);
        const bool p = (l >= off);
#pragma unroll
        for (int j = 0; j < 7; ++j) agg[j] += p ? t[j] : 0.0f;
    }
    float Lex[7];  // exclusive lane prefix
#pragma unroll
    for (int j = 0; j < 7; ++j) Lex[j] = agg[j] - loc[j];

    // object transmittance / weights
    float t_[4], T_[4], w_[4];
    const float TL = __expf(-Lex[0]);
#pragma unroll
    for (int s = 0; s < 4; ++s) t_[s] = __expf(-odd[s]);
    T_[0] = TL;
#pragma unroll
    for (int s = 1; s < 4; ++s) T_[s] = T_[s - 1] * t_[s - 1];
#pragma unroll
    for (int s = 0; s < 4; ++s) w_[s] = (1.0f - t_[s]) * T_[s];

    // partial reductions: [0..2] restored, [3..5] direct, [6..8] backscatter_obj, [9] wsum
    float red[10];
    red[9] = w_[0] + w_[1] + w_[2] + w_[3];
#pragma unroll
    for (int c = 0; c < 3; ++c) {
        const float BD = Lex[0] + Lex[1 + c];
        const float BB = Lex[0] + Lex[4 + c];
        float sr = 0.0f, sd = 0.0f, sb = 0.0f;
#pragma unroll
        for (int s = 0; s < 4; ++s) {
            const float g = rgbv[3 * s + c];
            const float v = vlv[3 * s + c];
            const float omt = 1.0f - t_[s];
            // w_s * direct_atten = (1-t_s) * exp(-(exO_s + exD_s))
            const float wda = omt * __expf(-(BD + cumO[s] + cumD[4 * c + s]));
            // w_s * backscatter_transmittance
            const float wbt = omt * __expf(-(BB + cumO[s] + cumB[4 * c + s]));
            sr += w_[s] * g;
            sd += wda * g;
            sb += (w_[s] - wbt) * v;
        }
        red[c] = sr;
        red[3 + c] = sd;
        red[6 + c] = sb;
    }

    // butterfly reduction within each 32-lane half (xor offsets <= 16 stay in half)
#pragma unroll
    for (int off = 16; off >= 1; off >>= 1) {
#pragma unroll
        for (int j = 0; j < 10; ++j) red[j] += __shfl_xor(red[j], off, 64);
    }

    // veiling_light at sample 0: lane 0 of this half holds vlv[0..2]
    float vl0[3];
#pragma unroll
    for (int c = 0; c < 3; ++c) vl0[c] = __shfl(vlv[c], sub << 5, 64);

    if (l < 3) {
        const int c = l;
        const float mask = fminf(fmaxf(red[9], 0.0f), 1.0f);
        const float bsr  = red[6 + c] + (1.0f - mask) * vl0[c];
        const size_t rc = (size_t)r * 3 + c;
        const size_t stride = (size_t)R * 3;
        out[rc]              = fminf(fmaxf(red[3 + c] + bsr, 0.0f), 1.0f); // rgb
        out[stride + rc]     = fminf(fmaxf(red[c],          0.0f), 1.0f); // restored
        out[2 * stride + rc] = fminf(fmaxf(red[3 + c],      0.0f), 1.0f); // direct
        out[3 * stride + rc] = fminf(fmaxf(bsr,             0.0f), 1.0f); // backscatter
    }
}

extern "C" void kernel_launch(void* const* d_in, const int* in_sizes, int n_in,
                              void* d_out, int out_size, void* d_ws, size_t ws_size,
                              hipStream_t stream) {
    const float* densities = (const float*)d_in[0];
    const float* rgbs      = (const float*)d_in[1];
    const float* veil      = (const float*)d_in[2];
    const float* dcoef     = (const float*)d_in[3];
    const float* bcoef     = (const float*)d_in[4];
    const float* deltas    = (const float*)d_in[5];
    float* out = (float*)d_out;

    const int R = in_sizes[0] / S;   // 65536
    dim3 grid((R + 7) / 8), block(256);
    uwnerf_render<<<grid, block, 0, stream>>>(densities, rgbs, veil, dcoef, bcoef,
                                              deltas, out, R);
}